// Round 13
// baseline (314.132 us; speedup 1.0000x reference)
//
#include <hip/hip_runtime.h>
#include <hip/hip_bf16.h>

#define EPS 1e-8f
#define LAMBDA 1e-3f
#define LN2PI_HALF 0.9189385332046727f

__device__ __forceinline__ float sigmoidf(float x) { return 1.f / (1.f + __expf(-x)); }

// ---------------------------------------------------------------------------
// 1) fused conv stem + primary caps v3 — full 30-oj row per block (grid 960),
//    ys_u[parity][j][c] layout, pose inner loop c-blocked x4.
// ---------------------------------------------------------------------------
__global__ __launch_bounds__(256) void stem_primary_kernel(
    const float* __restrict__ x, const float* __restrict__ w,
    const float* __restrict__ bias,
    const float* __restrict__ wp, const float* __restrict__ bp,
    const float* __restrict__ wa, const float* __restrict__ ba,
    float* __restrict__ pose, float* __restrict__ a) {
  __shared__ float wp_s[64][128];    // 32 KB
  __shared__ float wc_s[25][64];     // 6.4 KB
  __shared__ float wa_s[64][8];      // 2 KB
  __shared__ float bias_s[64];
  __shared__ float bp_s[128];
  __shared__ float ba_s[8];
  __shared__ float xs[5][63];
  __shared__ float ys_u[2][15][68];

  int t = threadIdx.x;
  int oi = blockIdx.x % 30;
  int b  = blockIdx.x / 30;

  for (int q = t; q < 8192; q += 256) ((float*)wp_s)[q] = wp[q];
  for (int q = t; q < 1600; q += 256) ((float*)wc_s)[q] = w[q];
  for (int q = t; q < 512;  q += 256) ((float*)wa_s)[q] = wa[q];
  if (t < 64) bias_s[t] = bias[t];
  if (t < 128) bp_s[t] = bp[t];
  if (t < 8) ba_s[t] = ba[t];
  for (int q = t; q < 315; q += 256) {
    int ki = q / 63, col = q % 63;
    xs[ki][col] = x[(b * 64 + 2 * oi + ki) * 64 + col];
  }
  __syncthreads();

  for (int q = t; q < 1920; q += 256) {
    int pos = q >> 6, ch = q & 63;
    float s = bias_s[ch];
#pragma unroll
    for (int ki = 0; ki < 5; ++ki)
#pragma unroll
      for (int kj = 0; kj < 5; ++kj)
        s += xs[ki][2 * pos + kj] * wc_s[ki * 5 + kj][ch];
    ys_u[pos & 1][pos >> 1][ch] = fmaxf(s, 0.f);
  }
  __syncthreads();

  int w_ = t >> 7, d = t & 127;
  float acc[15];
#pragma unroll
  for (int j = 0; j < 15; ++j) acc[j] = bp_s[d];
#pragma unroll 4
  for (int c4 = 0; c4 < 64; c4 += 4) {
    float w0 = wp_s[c4 + 0][d];
    float w1 = wp_s[c4 + 1][d];
    float w2 = wp_s[c4 + 2][d];
    float w3 = wp_s[c4 + 3][d];
#pragma unroll
    for (int j = 0; j < 15; ++j) {
      const float4 yv = *(const float4*)&ys_u[w_][j][c4];
      acc[j] += yv.x * w0 + yv.y * w1 + yv.z * w2 + yv.w * w3;
    }
  }
  size_t rowb = (size_t)(b * 30 + oi) * 30;
#pragma unroll
  for (int j = 0; j < 15; ++j)
    pose[(rowb + w_ + 2 * j) * 128 + d] = acc[j];

  if (t < 240) {
    int pos = t >> 3, jj = t & 7;
    float s = ba_s[jj];
#pragma unroll 8
    for (int c = 0; c < 64; ++c) s += ys_u[pos & 1][pos >> 1][c] * wa_s[c][jj];
    a[(rowb + pos) * 8 + jj] = sigmoidf(s);
  }
}

// ---------------------------------------------------------------------------
// 2) depthwise caps v3 (16-thr/output scalar version; v4 float4 variant
//    spilled VGPRs — do not revisit).
// ---------------------------------------------------------------------------
template <int K, int BC, int HIN, int WIN, int HOUT, int WOUT, int OIG, int NG>
__global__ __launch_bounds__(256) void dw_caps_kernel(
    const float* __restrict__ pose_in, const float* __restrict__ a_in,
    const float* __restrict__ Wt,
    const float* __restrict__ bu_p, const float* __restrict__ ba_p,
    float* __restrict__ pose_out, float* __restrict__ a_out) {
  constexpr int PAD = K / 2;
  constexpr int RA = (2 * (OIG - 1) + K < HIN) ? (2 * (OIG - 1) + K) : HIN;
  __shared__ float tp[RA * WIN * 20];
  __shared__ float ta[RA * WIN];
  __shared__ float wt[K * K * 16];

  int t = threadIdx.x;
  int g = (NG > 1) ? (blockIdx.x % NG) : 0;
  int c = (blockIdx.x / NG) % BC;
  int b = blockIdx.x / (NG * BC);
  int oi_lo = g * OIG;
  int rlo = max(0, 2 * oi_lo - PAD);
  int rhi = min(HIN, 2 * (oi_lo + OIG - 1) - PAD + K);
  int nrows = rhi - rlo;

  for (int q = t; q < K * K * 16; q += 256) {
    int tap = q >> 4, lj = q & 15, l = lj >> 2, j = lj & 3;
    wt[tap * 16 + lj] = Wt[((size_t)tap * BC + c) * 16 + j * 4 + l];
  }
  for (int q = t; q < nrows * WIN; q += 256) {
    int row = q / WIN, col = q % WIN;
    ta[q] = a_in[((size_t)((b * HIN + rlo + row) * WIN + col)) * BC + c];
  }
  for (int q = t; q < nrows * WIN * 4; q += 256) {
    int quad = q & 3, pc = q >> 2;
    int row = pc / WIN, col = pc % WIN;
    const float4 src = *(const float4*)(pose_in +
        (((size_t)((b * HIN + rlo + row) * WIN + col)) * BC + c) * 16 + quad * 4);
    *(float4*)(tp + (row * WIN + col) * 20 + quad * 4) = src;
  }
  __syncthreads();

  for (int s = t; s < OIG * WOUT * 16; s += 256) {
    int p = s & 15, pr = s >> 4;
    int oj = pr % WOUT;
    int oi = oi_lo + pr / WOUT;
    int ip = p >> 2, l = p & 3;
    int ih0 = 2 * oi - PAD, iw0 = 2 * oj - PAD;
    float rsum = 0.f, acc = 0.f, acc2 = 0.f;
#pragma unroll
    for (int ki = 0; ki < K; ++ki) {
      int ih = ih0 + ki;
      if (ih < 0 || ih >= HIN) continue;
      int rbase = (ih - rlo) * WIN;
#pragma unroll
      for (int kj = 0; kj < K; ++kj) {
        int iw = iw0 + kj;
        if (iw < 0 || iw >= WIN) continue;
        float ak = ta[rbase + iw];
        const float4 pm = *(const float4*)(tp + (rbase + iw) * 20 + ip * 4);
        const float4 wr = *(const float4*)(wt + (ki * K + kj) * 16 + l * 4);
        float v = pm.x * wr.x + pm.y * wr.y + pm.z * wr.z + pm.w * wr.w;
        rsum += ak;
        float av = ak * v;
        acc += av;
        acc2 += av * v;
      }
    }
    float inv = 1.f / (rsum + EPS);
    float mu = acc * inv;
    float S = rsum * inv;
    float sg = acc2 * inv - mu * mu * (2.f - S);
    sg = fmaxf(sg, 0.f) + EPS;
    float hl = 0.5f * __logf(sg);
    float ls = hl;
    ls += __shfl_xor(ls, 1, 64);
    ls += __shfl_xor(ls, 2, 64);
    ls += __shfl_xor(ls, 4, 64);
    ls += __shfl_xor(ls, 8, 64);

    size_t obase = ((size_t)(b * HOUT + oi) * WOUT + oj) * BC + c;
    pose_out[obase * 16 + p] = mu;
    if (p == 0) {
      float cost = rsum * (16.f * bu_p[0] + ls);
      a_out[obase] = sigmoidf(LAMBDA * (ba_p[0] - cost));
    }
  }
}

// ---------------------------------------------------------------------------
// 3) 1x1 conv caps EM v3.1 — one problem per wave, registers only.
//    NEW: `#pragma unroll 1` on the 3-iter EM loop. R12 counters (occupancy
//    30% despite full residency, VALUBusy 41%, no mem/LDS bottleneck) point
//    at I-cache thrash from the compiler 3x-unrolling the huge EM body.
// ---------------------------------------------------------------------------
template <int BIN>
__global__ __launch_bounds__(256) void cc_em_kernel(
    const float* __restrict__ pose_in, const float* __restrict__ a_arr,
    const float* __restrict__ Wt,
    const float* __restrict__ bu_p, const float* __restrict__ ba_p,
    float* __restrict__ pose_out, float* __restrict__ a_out) {
  constexpr int COUT = 16;
  __shared__ float wt_s[BIN * COUT * 20];
  int t = threadIdx.x;
  for (int idx = t; idx < BIN * COUT * 16; idx += 256) {
    int lk = idx & 15, l = lk >> 2, k = lk & 3;
    int bc = idx >> 4;
    wt_s[bc * 20 + l * 4 + k] = Wt[bc * 16 + k * 4 + l];
  }
  __syncthreads();

  int wave = t >> 6, lane = t & 63;
  int n = blockIdx.x * 4 + wave;
  int c = lane >> 2;
  int q = lane & 3;

  float ain[BIN], rw[BIN];
  float4 pmq[BIN];
#pragma unroll
  for (int b = 0; b < BIN; ++b) {
    ain[b] = a_arr[(size_t)n * BIN + b];
    rw[b] = (1.f / 16.f) * ain[b];
    pmq[b] = *(const float4*)(pose_in + (size_t)n * BIN * 16 + b * 16 + q * 4);
  }
  float bu = bu_p[c], ba = ba_p[c];

  float v[BIN][4];
#pragma unroll
  for (int b = 0; b < BIN; ++b) {
    const float* wr = wt_s + (b * 16 + c) * 20;
#pragma unroll
    for (int l = 0; l < 4; ++l) {
      const float4 w4 = *(const float4*)(wr + l * 4);
      v[b][l] = pmq[b].x * w4.x + pmq[b].y * w4.y + pmq[b].z * w4.z + pmq[b].w * w4.w;
    }
  }

  float mu[4], inv2[4], lsum = 0.f, ao = 0.f;
#pragma unroll 1
  for (int it = 0; it < 3; ++it) {
    float sA = 0.f, sV[4] = {0, 0, 0, 0}, sV2[4] = {0, 0, 0, 0};
#pragma unroll
    for (int b = 0; b < BIN; ++b) {
      sA += rw[b];
#pragma unroll
      for (int l = 0; l < 4; ++l) {
        float rv = rw[b] * v[b][l];
        sV[l] += rv;
        sV2[l] += rv * v[b][l];
      }
    }
    float inv = 1.f / (sA + EPS);
    float S = sA * inv;
    lsum = 0.f;
#pragma unroll
    for (int l = 0; l < 4; ++l) {
      mu[l] = sV[l] * inv;
      float sg = sV2[l] * inv - mu[l] * mu[l] * (2.f - S) + EPS;
      sg = fmaxf(sg, EPS);
      inv2[l] = 0.5f / sg;
      lsum += 0.5f * __logf(sg);
    }
    lsum += __shfl_xor(lsum, 1, 64);
    lsum += __shfl_xor(lsum, 2, 64);
    float cost = sA * (16.f * bu + lsum);
    ao = sigmoidf(LAMBDA * (ba - cost));

    if (it < 2) {
      float term[BIN];
#pragma unroll
      for (int b = 0; b < BIN; ++b) {
        float s = 0.f;
#pragma unroll
        for (int l = 0; l < 4; ++l) {
          float d = v[b][l] - mu[l];
          s += d * d * inv2[l];
        }
        term[b] = s;
      }
#pragma unroll
      for (int b = 0; b < BIN; ++b) {
        term[b] += __shfl_xor(term[b], 1, 64);
        term[b] += __shfl_xor(term[b], 2, 64);
      }
      float basec = __logf(EPS + ao) - lsum - 16.f * LN2PI_HALF;
      float lnap[BIN], Z[BIN];
#pragma unroll
      for (int b = 0; b < BIN; ++b) lnap[b] = basec - term[b];
      float mx[BIN];
#pragma unroll
      for (int b = 0; b < BIN; ++b) mx[b] = lnap[b];
#pragma unroll
      for (int m = 4; m < 64; m <<= 1)
#pragma unroll
        for (int b = 0; b < BIN; ++b) mx[b] = fmaxf(mx[b], __shfl_xor(mx[b], m, 64));
#pragma unroll
      for (int b = 0; b < BIN; ++b) { lnap[b] = __expf(lnap[b] - mx[b]); Z[b] = lnap[b]; }
#pragma unroll
      for (int m = 4; m < 64; m <<= 1)
#pragma unroll
        for (int b = 0; b < BIN; ++b) Z[b] += __shfl_xor(Z[b], m, 64);
#pragma unroll
      for (int b = 0; b < BIN; ++b) rw[b] = lnap[b] / Z[b] * ain[b];
    }
  }
  float4 om = make_float4(mu[0], mu[1], mu[2], mu[3]);
  *(float4*)(pose_out + (size_t)n * 256 + c * 16 + q * 4) = om;
  if (q == 0) a_out[(size_t)n * COUT + c] = ao;
}

// ---------------------------------------------------------------------------
// 4) class caps FUSED E+M: one 256-thread block per (image b, capsule c).
//    first=1: rw = 0.1*a5 (iteration 0 M). Else: recompute the full
//    10-capsule softmax per b_in from prev-state (mu_i/inv2_i/base_i) —
//    10x vote FLOPs but removes 2 dispatches (~10 us fixed cost each) and
//    the X round-trip. Ping-pong state buffers avoid same-image races.
// ---------------------------------------------------------------------------
__global__ __launch_bounds__(256) void cls_em_kernel(
    const float* __restrict__ pose5, const float* __restrict__ a5,
    const float* __restrict__ W,
    const float* __restrict__ bu_p, const float* __restrict__ ba_p,
    const float* __restrict__ mu_i, const float* __restrict__ inv2_i,
    const float* __restrict__ base_i,
    float* __restrict__ mu_o, float* __restrict__ inv2_o,
    float* __restrict__ base_o, float* __restrict__ out,
    int first, int last) {
  int blk = blockIdx.x;                 // b*10 + c
  int c = blk % 10, b = blk / 10;
  int t = threadIdx.x;
  int lane = t & 63, wv = t >> 6;
  const float* pg = pose5 + (size_t)b * 16384;
  __shared__ float w2[10][16][16];      // [c][jj][d] — lane-varying d contiguous
  __shared__ float mu_s[160];
  __shared__ float inv2_s[160];
  __shared__ float base_s[10];
  for (int q = t; q < 2560; q += 256) {
    int dd = q & 15, jj = (q >> 4) & 15, c2 = q >> 8;
    w2[c2][jj][dd] = W[(dd * 10 + c2) * 16 + jj];
  }
  if (!first) {
    if (t < 160) { mu_s[t] = mu_i[b * 160 + t]; inv2_s[t] = inv2_i[b * 160 + t]; }
    if (t >= 160 && t < 170) base_s[t - 160] = base_i[b * 10 + (t - 160)];
  }
  __syncthreads();

  const int d = t & 15;                 // b_in = rep*256+t keeps d fixed
  float wf[16];                         // own-c weights for the moment votes
#pragma unroll
  for (int jj = 0; jj < 16; ++jj) wf[jj] = w2[c][jj][d];

  float sA = 0.f, sV[16], sV2[16];
#pragma unroll
  for (int p = 0; p < 16; ++p) { sV[p] = 0.f; sV2[p] = 0.f; }
#pragma unroll 1
  for (int rep = 0; rep < 4; ++rep) {
    int bi = rep * 256 + t;
    int pos = bi >> 4;
    float ci = (float)(pos >> 3) * 0.125f;
    float cj = (float)(pos & 7) * 0.125f;
    const float* pp = pg + pos * 256 + d * 16;
    float pmr[16];
#pragma unroll
    for (int q = 0; q < 16; ++q) pmr[q] = pp[q];
    float av = a5[(size_t)b * 1024 + bi];
    float rw;
    if (first) {
      rw = 0.1f * av;
    } else {
      // E-step recompute: lnap over all 10 capsules
      float lnap[10];
#pragma unroll
      for (int c2 = 0; c2 < 10; ++c2) {
        float s = base_s[c2];
#pragma unroll
        for (int p = 0; p < 16; ++p) {
          int ip = p >> 2, l = p & 3;
          float v = pmr[ip * 4 + 0] * w2[c2][0 * 4 + l][d]
                  + pmr[ip * 4 + 1] * w2[c2][1 * 4 + l][d]
                  + pmr[ip * 4 + 2] * w2[c2][2 * 4 + l][d]
                  + pmr[ip * 4 + 3] * w2[c2][3 * 4 + l][d];
          if (p == 0) v += ci;
          else if (p == 1) v += cj;
          float dd2 = v - mu_s[c2 * 16 + p];
          s -= dd2 * dd2 * inv2_s[c2 * 16 + p];
        }
        lnap[c2] = s;
      }
      float m = -1e30f;
#pragma unroll
      for (int c2 = 0; c2 < 10; ++c2) m = fmaxf(m, lnap[c2]);
      float Z = 0.f;
      float exc = 0.f;
#pragma unroll
      for (int c2 = 0; c2 < 10; ++c2) {
        float e = __expf(lnap[c2] - m);
        Z += e;
        if (c2 == c) exc = e;
      }
      rw = exc / Z * av;
    }
    sA += rw;
    // own-c votes for moments
#pragma unroll
    for (int p = 0; p < 16; ++p) {
      int ip = p >> 2, l = p & 3;
      float v = pmr[ip * 4 + 0] * wf[0 * 4 + l] + pmr[ip * 4 + 1] * wf[1 * 4 + l]
              + pmr[ip * 4 + 2] * wf[2 * 4 + l] + pmr[ip * 4 + 3] * wf[3 * 4 + l];
      if (p == 0) v += ci;
      else if (p == 1) v += cj;
      float rv = rw * v;
      sV[p] += rv;
      sV2[p] += rv * v;
    }
  }
#pragma unroll
  for (int off = 1; off < 64; off <<= 1) {
    sA += __shfl_xor(sA, off, 64);
#pragma unroll
    for (int p = 0; p < 16; ++p) {
      sV[p]  += __shfl_xor(sV[p],  off, 64);
      sV2[p] += __shfl_xor(sV2[p], off, 64);
    }
  }
  __shared__ float red[4][36];
  if (lane == 0) {
    red[wv][0] = sA;
#pragma unroll
    for (int p = 0; p < 16; ++p) { red[wv][1 + p] = sV[p]; red[wv][17 + p] = sV2[p]; }
  }
  __syncthreads();
  if (t < 16) {
    int p = t;
    float sAf  = red[0][0] + red[1][0] + red[2][0] + red[3][0];
    float sVf  = red[0][1+p] + red[1][1+p] + red[2][1+p] + red[3][1+p];
    float sV2f = red[0][17+p] + red[1][17+p] + red[2][17+p] + red[3][17+p];
    float inv = 1.f / (sAf + EPS);
    float S = sAf * inv;
    float mu = sVf * inv;
    float sg = sV2f * inv - mu * mu * (2.f - S) + EPS;
    sg = fmaxf(sg, EPS);
    mu_o[blk * 16 + p] = mu;
    inv2_o[blk * 16 + p] = 0.5f / sg;
    float hl = 0.5f * __logf(sg);
    float lsum = hl;
    lsum += __shfl_xor(lsum, 1, 64);
    lsum += __shfl_xor(lsum, 2, 64);
    lsum += __shfl_xor(lsum, 4, 64);
    lsum += __shfl_xor(lsum, 8, 64);
    if (p == 0) {
      float cost = sAf * (16.f * bu_p[c] + lsum);
      float ao = sigmoidf(LAMBDA * (ba_p[c] - cost));
      base_o[blk] = __logf(EPS + ao) - lsum - 16.f * LN2PI_HALF;
      if (last) out[blk] = ao;
    }
  }
}

// ---------------------------------------------------------------------------
extern "C" void kernel_launch(void* const* d_in, const int* in_sizes, int n_in,
                              void* d_out, int out_size, void* d_ws, size_t ws_size,
                              hipStream_t stream) {
  const float* x       = (const float*)d_in[0];
  const float* conv1_w = (const float*)d_in[1];
  const float* conv1_b = (const float*)d_in[2];
  const float* pp_w    = (const float*)d_in[3];
  const float* pp_b    = (const float*)d_in[4];
  const float* pa_w    = (const float*)d_in[5];
  const float* pa_b    = (const float*)d_in[6];
  const float* dw1_w   = (const float*)d_in[7];
  const float* dw1_bu  = (const float*)d_in[8];
  const float* dw1_ba  = (const float*)d_in[9];
  const float* cc1_w   = (const float*)d_in[10];
  const float* cc1_bu  = (const float*)d_in[11];
  const float* cc1_ba  = (const float*)d_in[12];
  const float* dw2_w   = (const float*)d_in[13];
  const float* dw2_bu  = (const float*)d_in[14];
  const float* dw2_ba  = (const float*)d_in[15];
  const float* cc2_w   = (const float*)d_in[16];
  const float* cc2_bu  = (const float*)d_in[17];
  const float* cc2_ba  = (const float*)d_in[18];
  const float* cls_w   = (const float*)d_in[19];
  const float* cls_bu  = (const float*)d_in[20];
  const float* cls_ba  = (const float*)d_in[21];
  float* out = (float*)d_out;

  float* ws = (float*)d_ws;
  float* pose1 = ws;                  // 32*30*30*128
  float* a1    = ws + 3686400;        // 32*30*30*8
  float* pose2 = ws + 3916800;        // 32*15*15*128
  float* a2    = ws + 4838400;        // 32*15*15*8
  float* pose3 = ws;                  // 32*15*15*256 (aliases dead pose1)
  float* a3    = ws + 1843200;        // 32*15*15*16
  float* pose4 = ws + 1958400;        // 32*8*8*256
  float* a4    = ws + 2482688;        // 32*8*8*16
  float* pose5 = ws + 2515456;        // 32*8*8*256
  float* a5    = ws + 3039744;        // 32*8*8*16
  float* muA   = ws + 3072512;        // 32*160
  float* inv2A = ws + 3077632;        // 32*160
  float* baseA = ws + 3082752;        // 32*10
  float* muB   = ws + 3083072;        // 32*160
  float* inv2B = ws + 3088192;        // 32*160
  float* baseB = ws + 3093312;        // 32*10

  stem_primary_kernel<<<960, 256, 0, stream>>>(x, conv1_w, conv1_b,
                                               pp_w, pp_b, pa_w, pa_b, pose1, a1);
  dw_caps_kernel<7, 8, 30, 30, 15, 15, 5, 3><<<768, 256, 0, stream>>>(
      pose1, a1, dw1_w, dw1_bu, dw1_ba, pose2, a2);
  cc_em_kernel<8><<<1800, 256, 0, stream>>>(pose2, a2, cc1_w, cc1_bu, cc1_ba, pose3, a3);
  dw_caps_kernel<5, 16, 15, 15, 8, 8, 8, 1><<<512, 256, 0, stream>>>(
      pose3, a3, dw2_w, dw2_bu, dw2_ba, pose4, a4);
  cc_em_kernel<16><<<512, 256, 0, stream>>>(pose4, a4, cc2_w, cc2_bu, cc2_ba, pose5, a5);
  // class caps: fused E+M, ping-pong state — 3 dispatches (was 5)
  cls_em_kernel<<<320, 256, 0, stream>>>(pose5, a5, cls_w, cls_bu, cls_ba,
                                         nullptr, nullptr, nullptr,
                                         muA, inv2A, baseA, out, 1, 0);
  cls_em_kernel<<<320, 256, 0, stream>>>(pose5, a5, cls_w, cls_bu, cls_ba,
                                         muA, inv2A, baseA,
                                         muB, inv2B, baseB, out, 0, 0);
  cls_em_kernel<<<320, 256, 0, stream>>>(pose5, a5, cls_w, cls_bu, cls_ba,
                                         muB, inv2B, baseB,
                                         muA, inv2A, baseA, out, 0, 1);
}

// Round 14
// 263.485 us; speedup vs baseline: 1.1922x; 1.1922x over previous
//
#include <hip/hip_runtime.h>
#include <hip/hip_bf16.h>

#define EPS 1e-8f
#define LAMBDA 1e-3f
#define LN2PI_HALF 0.9189385332046727f

__device__ __forceinline__ float sigmoidf(float x) { return 1.f / (1.f + __expf(-x)); }

// ---------------------------------------------------------------------------
// 1) fused conv stem + primary caps v3 — full 30-oj row per block (grid 960),
//    ys_u[parity][j][c] layout, pose inner loop c-blocked x4.
// ---------------------------------------------------------------------------
__global__ __launch_bounds__(256) void stem_primary_kernel(
    const float* __restrict__ x, const float* __restrict__ w,
    const float* __restrict__ bias,
    const float* __restrict__ wp, const float* __restrict__ bp,
    const float* __restrict__ wa, const float* __restrict__ ba,
    float* __restrict__ pose, float* __restrict__ a) {
  __shared__ float wp_s[64][128];    // 32 KB
  __shared__ float wc_s[25][64];     // 6.4 KB
  __shared__ float wa_s[64][8];      // 2 KB
  __shared__ float bias_s[64];
  __shared__ float bp_s[128];
  __shared__ float ba_s[8];
  __shared__ float xs[5][63];
  __shared__ float ys_u[2][15][68];

  int t = threadIdx.x;
  int oi = blockIdx.x % 30;
  int b  = blockIdx.x / 30;

  for (int q = t; q < 8192; q += 256) ((float*)wp_s)[q] = wp[q];
  for (int q = t; q < 1600; q += 256) ((float*)wc_s)[q] = w[q];
  for (int q = t; q < 512;  q += 256) ((float*)wa_s)[q] = wa[q];
  if (t < 64) bias_s[t] = bias[t];
  if (t < 128) bp_s[t] = bp[t];
  if (t < 8) ba_s[t] = ba[t];
  for (int q = t; q < 315; q += 256) {
    int ki = q / 63, col = q % 63;
    xs[ki][col] = x[(b * 64 + 2 * oi + ki) * 64 + col];
  }
  __syncthreads();

  for (int q = t; q < 1920; q += 256) {
    int pos = q >> 6, ch = q & 63;
    float s = bias_s[ch];
#pragma unroll
    for (int ki = 0; ki < 5; ++ki)
#pragma unroll
      for (int kj = 0; kj < 5; ++kj)
        s += xs[ki][2 * pos + kj] * wc_s[ki * 5 + kj][ch];
    ys_u[pos & 1][pos >> 1][ch] = fmaxf(s, 0.f);
  }
  __syncthreads();

  int w_ = t >> 7, d = t & 127;
  float acc[15];
#pragma unroll
  for (int j = 0; j < 15; ++j) acc[j] = bp_s[d];
#pragma unroll 4
  for (int c4 = 0; c4 < 64; c4 += 4) {
    float w0 = wp_s[c4 + 0][d];
    float w1 = wp_s[c4 + 1][d];
    float w2 = wp_s[c4 + 2][d];
    float w3 = wp_s[c4 + 3][d];
#pragma unroll
    for (int j = 0; j < 15; ++j) {
      const float4 yv = *(const float4*)&ys_u[w_][j][c4];
      acc[j] += yv.x * w0 + yv.y * w1 + yv.z * w2 + yv.w * w3;
    }
  }
  size_t rowb = (size_t)(b * 30 + oi) * 30;
#pragma unroll
  for (int j = 0; j < 15; ++j)
    pose[(rowb + w_ + 2 * j) * 128 + d] = acc[j];

  if (t < 240) {
    int pos = t >> 3, jj = t & 7;
    float s = ba_s[jj];
#pragma unroll 8
    for (int c = 0; c < 64; ++c) s += ys_u[pos & 1][pos >> 1][c] * wa_s[c][jj];
    a[(rowb + pos) * 8 + jj] = sigmoidf(s);
  }
}

// ---------------------------------------------------------------------------
// 2) depthwise caps v3 (16-thr/output scalar; v4 float4 variant spilled).
// ---------------------------------------------------------------------------
template <int K, int BC, int HIN, int WIN, int HOUT, int WOUT, int OIG, int NG>
__global__ __launch_bounds__(256) void dw_caps_kernel(
    const float* __restrict__ pose_in, const float* __restrict__ a_in,
    const float* __restrict__ Wt,
    const float* __restrict__ bu_p, const float* __restrict__ ba_p,
    float* __restrict__ pose_out, float* __restrict__ a_out) {
  constexpr int PAD = K / 2;
  constexpr int RA = (2 * (OIG - 1) + K < HIN) ? (2 * (OIG - 1) + K) : HIN;
  __shared__ float tp[RA * WIN * 20];
  __shared__ float ta[RA * WIN];
  __shared__ float wt[K * K * 16];

  int t = threadIdx.x;
  int g = (NG > 1) ? (blockIdx.x % NG) : 0;
  int c = (blockIdx.x / NG) % BC;
  int b = blockIdx.x / (NG * BC);
  int oi_lo = g * OIG;
  int rlo = max(0, 2 * oi_lo - PAD);
  int rhi = min(HIN, 2 * (oi_lo + OIG - 1) - PAD + K);
  int nrows = rhi - rlo;

  for (int q = t; q < K * K * 16; q += 256) {
    int tap = q >> 4, lj = q & 15, l = lj >> 2, j = lj & 3;
    wt[tap * 16 + lj] = Wt[((size_t)tap * BC + c) * 16 + j * 4 + l];
  }
  for (int q = t; q < nrows * WIN; q += 256) {
    int row = q / WIN, col = q % WIN;
    ta[q] = a_in[((size_t)((b * HIN + rlo + row) * WIN + col)) * BC + c];
  }
  for (int q = t; q < nrows * WIN * 4; q += 256) {
    int quad = q & 3, pc = q >> 2;
    int row = pc / WIN, col = pc % WIN;
    const float4 src = *(const float4*)(pose_in +
        (((size_t)((b * HIN + rlo + row) * WIN + col)) * BC + c) * 16 + quad * 4);
    *(float4*)(tp + (row * WIN + col) * 20 + quad * 4) = src;
  }
  __syncthreads();

  for (int s = t; s < OIG * WOUT * 16; s += 256) {
    int p = s & 15, pr = s >> 4;
    int oj = pr % WOUT;
    int oi = oi_lo + pr / WOUT;
    int ip = p >> 2, l = p & 3;
    int ih0 = 2 * oi - PAD, iw0 = 2 * oj - PAD;
    float rsum = 0.f, acc = 0.f, acc2 = 0.f;
#pragma unroll
    for (int ki = 0; ki < K; ++ki) {
      int ih = ih0 + ki;
      if (ih < 0 || ih >= HIN) continue;
      int rbase = (ih - rlo) * WIN;
#pragma unroll
      for (int kj = 0; kj < K; ++kj) {
        int iw = iw0 + kj;
        if (iw < 0 || iw >= WIN) continue;
        float ak = ta[rbase + iw];
        const float4 pm = *(const float4*)(tp + (rbase + iw) * 20 + ip * 4);
        const float4 wr = *(const float4*)(wt + (ki * K + kj) * 16 + l * 4);
        float v = pm.x * wr.x + pm.y * wr.y + pm.z * wr.z + pm.w * wr.w;
        rsum += ak;
        float av = ak * v;
        acc += av;
        acc2 += av * v;
      }
    }
    float inv = 1.f / (rsum + EPS);
    float mu = acc * inv;
    float S = rsum * inv;
    float sg = acc2 * inv - mu * mu * (2.f - S);
    sg = fmaxf(sg, 0.f) + EPS;
    float hl = 0.5f * __logf(sg);
    float ls = hl;
    ls += __shfl_xor(ls, 1, 64);
    ls += __shfl_xor(ls, 2, 64);
    ls += __shfl_xor(ls, 4, 64);
    ls += __shfl_xor(ls, 8, 64);

    size_t obase = ((size_t)(b * HOUT + oi) * WOUT + oj) * BC + c;
    pose_out[obase * 16 + p] = mu;
    if (p == 0) {
      float cost = rsum * (16.f * bu_p[0] + ls);
      a_out[obase] = sigmoidf(LAMBDA * (ba_p[0] - cost));
    }
  }
}

// ---------------------------------------------------------------------------
// 3) 1x1 conv caps EM v3.1 — one problem per wave, registers only,
//    `#pragma unroll 1` on the EM loop (I-cache: confirmed ~25 us win in R13).
// ---------------------------------------------------------------------------
template <int BIN>
__global__ __launch_bounds__(256) void cc_em_kernel(
    const float* __restrict__ pose_in, const float* __restrict__ a_arr,
    const float* __restrict__ Wt,
    const float* __restrict__ bu_p, const float* __restrict__ ba_p,
    float* __restrict__ pose_out, float* __restrict__ a_out) {
  constexpr int COUT = 16;
  __shared__ float wt_s[BIN * COUT * 20];
  int t = threadIdx.x;
  for (int idx = t; idx < BIN * COUT * 16; idx += 256) {
    int lk = idx & 15, l = lk >> 2, k = lk & 3;
    int bc = idx >> 4;
    wt_s[bc * 20 + l * 4 + k] = Wt[bc * 16 + k * 4 + l];
  }
  __syncthreads();

  int wave = t >> 6, lane = t & 63;
  int n = blockIdx.x * 4 + wave;
  int c = lane >> 2;
  int q = lane & 3;

  float ain[BIN], rw[BIN];
  float4 pmq[BIN];
#pragma unroll
  for (int b = 0; b < BIN; ++b) {
    ain[b] = a_arr[(size_t)n * BIN + b];
    rw[b] = (1.f / 16.f) * ain[b];
    pmq[b] = *(const float4*)(pose_in + (size_t)n * BIN * 16 + b * 16 + q * 4);
  }
  float bu = bu_p[c], ba = ba_p[c];

  float v[BIN][4];
#pragma unroll
  for (int b = 0; b < BIN; ++b) {
    const float* wr = wt_s + (b * 16 + c) * 20;
#pragma unroll
    for (int l = 0; l < 4; ++l) {
      const float4 w4 = *(const float4*)(wr + l * 4);
      v[b][l] = pmq[b].x * w4.x + pmq[b].y * w4.y + pmq[b].z * w4.z + pmq[b].w * w4.w;
    }
  }

  float mu[4], inv2[4], lsum = 0.f, ao = 0.f;
#pragma unroll 1
  for (int it = 0; it < 3; ++it) {
    float sA = 0.f, sV[4] = {0, 0, 0, 0}, sV2[4] = {0, 0, 0, 0};
#pragma unroll
    for (int b = 0; b < BIN; ++b) {
      sA += rw[b];
#pragma unroll
      for (int l = 0; l < 4; ++l) {
        float rv = rw[b] * v[b][l];
        sV[l] += rv;
        sV2[l] += rv * v[b][l];
      }
    }
    float inv = 1.f / (sA + EPS);
    float S = sA * inv;
    lsum = 0.f;
#pragma unroll
    for (int l = 0; l < 4; ++l) {
      mu[l] = sV[l] * inv;
      float sg = sV2[l] * inv - mu[l] * mu[l] * (2.f - S) + EPS;
      sg = fmaxf(sg, EPS);
      inv2[l] = 0.5f / sg;
      lsum += 0.5f * __logf(sg);
    }
    lsum += __shfl_xor(lsum, 1, 64);
    lsum += __shfl_xor(lsum, 2, 64);
    float cost = sA * (16.f * bu + lsum);
    ao = sigmoidf(LAMBDA * (ba - cost));

    if (it < 2) {
      float term[BIN];
#pragma unroll
      for (int b = 0; b < BIN; ++b) {
        float s = 0.f;
#pragma unroll
        for (int l = 0; l < 4; ++l) {
          float d = v[b][l] - mu[l];
          s += d * d * inv2[l];
        }
        term[b] = s;
      }
#pragma unroll
      for (int b = 0; b < BIN; ++b) {
        term[b] += __shfl_xor(term[b], 1, 64);
        term[b] += __shfl_xor(term[b], 2, 64);
      }
      float basec = __logf(EPS + ao) - lsum - 16.f * LN2PI_HALF;
      float lnap[BIN], Z[BIN];
#pragma unroll
      for (int b = 0; b < BIN; ++b) lnap[b] = basec - term[b];
      float mx[BIN];
#pragma unroll
      for (int b = 0; b < BIN; ++b) mx[b] = lnap[b];
#pragma unroll
      for (int m = 4; m < 64; m <<= 1)
#pragma unroll
        for (int b = 0; b < BIN; ++b) mx[b] = fmaxf(mx[b], __shfl_xor(mx[b], m, 64));
#pragma unroll
      for (int b = 0; b < BIN; ++b) { lnap[b] = __expf(lnap[b] - mx[b]); Z[b] = lnap[b]; }
#pragma unroll
      for (int m = 4; m < 64; m <<= 1)
#pragma unroll
        for (int b = 0; b < BIN; ++b) Z[b] += __shfl_xor(Z[b], m, 64);
#pragma unroll
      for (int b = 0; b < BIN; ++b) rw[b] = lnap[b] / Z[b] * ain[b];
    }
  }
  float4 om = make_float4(mu[0], mu[1], mu[2], mu[3]);
  *(float4*)(pose_out + (size_t)n * 256 + c * 16 + q * 4) = om;
  if (q == 0) a_out[(size_t)n * COUT + c] = ao;
}

// ---------------------------------------------------------------------------
// 4a) class caps M-step (R12 split version — REVERTED from the fused E+M,
//     which hit VGPR=240 / 6% occupancy / 45 us x2). One 256-thr block per
//     (image b, capsule c); ~3-5 us per dispatch.
// ---------------------------------------------------------------------------
__global__ __launch_bounds__(256) void cls_m_kernel(
    const float* __restrict__ pose5, const float* __restrict__ a5,
    const float* __restrict__ X, const float* __restrict__ W,
    const float* __restrict__ bu_p, const float* __restrict__ ba_p,
    float* __restrict__ mu_g, float* __restrict__ inv2_g,
    float* __restrict__ base_g, float* __restrict__ out,
    int first, int last) {
  int blk = blockIdx.x;                 // b*10 + c
  int c = blk % 10, b = blk / 10;
  int t = threadIdx.x;
  int lane = t & 63, wv = t >> 6;
  const float* pg = pose5 + (size_t)b * 16384;
  __shared__ float w_s[16][16];         // [jj][d]
  {
    int d = t & 15, jj = t >> 4;
    w_s[jj][d] = W[(d * 10 + c) * 16 + jj];
  }
  __syncthreads();
  const int d = t & 15;
  float wf[16];
#pragma unroll
  for (int jj = 0; jj < 16; ++jj) wf[jj] = w_s[jj][d];

  float sA = 0.f, sV[16], sV2[16];
#pragma unroll
  for (int p = 0; p < 16; ++p) { sV[p] = 0.f; sV2[p] = 0.f; }
#pragma unroll 1
  for (int rep = 0; rep < 4; ++rep) {
    int bi = rep * 256 + t;
    int pos = bi >> 4;
    float rw = first ? 0.1f * a5[(size_t)b * 1024 + bi]
                     : X[(size_t)blk * 1024 + bi];
    float ci = (float)(pos >> 3) * 0.125f;
    float cj = (float)(pos & 7) * 0.125f;
    const float* pp = pg + pos * 256 + d * 16;
    float pmr[16];
#pragma unroll
    for (int q = 0; q < 16; ++q) pmr[q] = pp[q];
    sA += rw;
#pragma unroll
    for (int p = 0; p < 16; ++p) {
      int ip = p >> 2, l = p & 3;
      float v = pmr[ip * 4 + 0] * wf[0 * 4 + l] + pmr[ip * 4 + 1] * wf[1 * 4 + l]
              + pmr[ip * 4 + 2] * wf[2 * 4 + l] + pmr[ip * 4 + 3] * wf[3 * 4 + l];
      if (p == 0) v += ci;
      else if (p == 1) v += cj;
      float rv = rw * v;
      sV[p] += rv;
      sV2[p] += rv * v;
    }
  }
#pragma unroll
  for (int off = 1; off < 64; off <<= 1) {
    sA += __shfl_xor(sA, off, 64);
#pragma unroll
    for (int p = 0; p < 16; ++p) {
      sV[p]  += __shfl_xor(sV[p],  off, 64);
      sV2[p] += __shfl_xor(sV2[p], off, 64);
    }
  }
  __shared__ float red[4][36];
  if (lane == 0) {
    red[wv][0] = sA;
#pragma unroll
    for (int p = 0; p < 16; ++p) { red[wv][1 + p] = sV[p]; red[wv][17 + p] = sV2[p]; }
  }
  __syncthreads();
  if (t < 16) {
    int p = t;
    float sAf  = red[0][0] + red[1][0] + red[2][0] + red[3][0];
    float sVf  = red[0][1+p] + red[1][1+p] + red[2][1+p] + red[3][1+p];
    float sV2f = red[0][17+p] + red[1][17+p] + red[2][17+p] + red[3][17+p];
    float inv = 1.f / (sAf + EPS);
    float S = sAf * inv;
    float mu = sVf * inv;
    float sg = sV2f * inv - mu * mu * (2.f - S) + EPS;
    sg = fmaxf(sg, EPS);
    mu_g[blk * 16 + p] = mu;
    inv2_g[blk * 16 + p] = 0.5f / sg;
    float hl = 0.5f * __logf(sg);
    float lsum = hl;
    lsum += __shfl_xor(lsum, 1, 64);
    lsum += __shfl_xor(lsum, 2, 64);
    lsum += __shfl_xor(lsum, 4, 64);
    lsum += __shfl_xor(lsum, 8, 64);
    if (p == 0) {
      float cost = sAf * (16.f * bu_p[c] + lsum);
      float ao = sigmoidf(LAMBDA * (ba_p[c] - cost));
      base_g[blk] = __logf(EPS + ao) - lsum - 16.f * LN2PI_HALF;
      if (last) out[blk] = ao;
    }
  }
}

// ---------------------------------------------------------------------------
// 4b) class caps E-step (R12 split version): 2 blocks of 512 per image.
// ---------------------------------------------------------------------------
__global__ __launch_bounds__(512) void cls_e_kernel(
    const float* __restrict__ pose5, const float* __restrict__ a5,
    const float* __restrict__ W,
    const float* __restrict__ mu_g, const float* __restrict__ inv2_g,
    const float* __restrict__ base_g, float* __restrict__ X) {
  int b = blockIdx.x >> 1;
  int t = threadIdx.x;
  int bi = ((blockIdx.x & 1) << 9) + t;
  const float* pg = pose5 + (size_t)b * 16384;
  __shared__ float w2[10][16][16];      // [c][jj][d]
  __shared__ float mu_s[160];
  __shared__ float inv2_s[160];
  __shared__ float base_s[10];
  for (int q = t; q < 2560; q += 512) {
    int dd = q & 15, jj = (q >> 4) & 15, c = q >> 8;
    w2[c][jj][dd] = W[(dd * 10 + c) * 16 + jj];
  }
  if (t < 160) { mu_s[t] = mu_g[b * 160 + t]; inv2_s[t] = inv2_g[b * 160 + t]; }
  if (t >= 160 && t < 170) base_s[t - 160] = base_g[b * 10 + (t - 160)];
  __syncthreads();

  int pos = bi >> 4, d2 = bi & 15;
  float ci = (float)(pos >> 3) * 0.125f;
  float cj = (float)(pos & 7) * 0.125f;
  const float* pp = pg + pos * 256 + d2 * 16;
  float pmr[16];
#pragma unroll
  for (int q = 0; q < 16; ++q) pmr[q] = pp[q];
  float lnap[10];
#pragma unroll 1
  for (int c = 0; c < 10; ++c) {
    float wf[16];
#pragma unroll
    for (int jj = 0; jj < 16; ++jj) wf[jj] = w2[c][jj][d2];
    float s = base_s[c];
#pragma unroll
    for (int p = 0; p < 16; ++p) {
      int ip = p >> 2, l = p & 3;
      float v = pmr[ip * 4 + 0] * wf[0 * 4 + l] + pmr[ip * 4 + 1] * wf[1 * 4 + l]
              + pmr[ip * 4 + 2] * wf[2 * 4 + l] + pmr[ip * 4 + 3] * wf[3 * 4 + l];
      if (p == 0) v += ci;
      else if (p == 1) v += cj;
      float dd = v - mu_s[c * 16 + p];
      s -= dd * dd * inv2_s[c * 16 + p];
    }
    lnap[c] = s;
  }
  float m = -1e30f;
#pragma unroll
  for (int c = 0; c < 10; ++c) m = fmaxf(m, lnap[c]);
  float Z = 0.f;
  float ex[10];
#pragma unroll
  for (int c = 0; c < 10; ++c) { ex[c] = __expf(lnap[c] - m); Z += ex[c]; }
  float invZ = a5[(size_t)b * 1024 + bi] / Z;
#pragma unroll
  for (int c = 0; c < 10; ++c) X[((size_t)(b * 10 + c)) * 1024 + bi] = ex[c] * invZ;
}

// ---------------------------------------------------------------------------
extern "C" void kernel_launch(void* const* d_in, const int* in_sizes, int n_in,
                              void* d_out, int out_size, void* d_ws, size_t ws_size,
                              hipStream_t stream) {
  const float* x       = (const float*)d_in[0];
  const float* conv1_w = (const float*)d_in[1];
  const float* conv1_b = (const float*)d_in[2];
  const float* pp_w    = (const float*)d_in[3];
  const float* pp_b    = (const float*)d_in[4];
  const float* pa_w    = (const float*)d_in[5];
  const float* pa_b    = (const float*)d_in[6];
  const float* dw1_w   = (const float*)d_in[7];
  const float* dw1_bu  = (const float*)d_in[8];
  const float* dw1_ba  = (const float*)d_in[9];
  const float* cc1_w   = (const float*)d_in[10];
  const float* cc1_bu  = (const float*)d_in[11];
  const float* cc1_ba  = (const float*)d_in[12];
  const float* dw2_w   = (const float*)d_in[13];
  const float* dw2_bu  = (const float*)d_in[14];
  const float* dw2_ba  = (const float*)d_in[15];
  const float* cc2_w   = (const float*)d_in[16];
  const float* cc2_bu  = (const float*)d_in[17];
  const float* cc2_ba  = (const float*)d_in[18];
  const float* cls_w   = (const float*)d_in[19];
  const float* cls_bu  = (const float*)d_in[20];
  const float* cls_ba  = (const float*)d_in[21];
  float* out = (float*)d_out;

  float* ws = (float*)d_ws;
  float* pose1 = ws;                  // 32*30*30*128
  float* a1    = ws + 3686400;        // 32*30*30*8
  float* pose2 = ws + 3916800;        // 32*15*15*128
  float* a2    = ws + 4838400;        // 32*15*15*8
  float* pose3 = ws;                  // 32*15*15*256 (aliases dead pose1)
  float* a3    = ws + 1843200;        // 32*15*15*16
  float* pose4 = ws + 1958400;        // 32*8*8*256
  float* a4    = ws + 2482688;        // 32*8*8*16
  float* pose5 = ws + 2515456;        // 32*8*8*256
  float* a5    = ws + 3039744;        // 32*8*8*16
  float* Xbuf  = ws + 3072512;        // 32*10*1024
  float* mu_g  = ws + 3400192;        // 32*160
  float* inv2_g= ws + 3405312;        // 32*160
  float* base_g= ws + 3410432;        // 32*10

  stem_primary_kernel<<<960, 256, 0, stream>>>(x, conv1_w, conv1_b,
                                               pp_w, pp_b, pa_w, pa_b, pose1, a1);
  dw_caps_kernel<7, 8, 30, 30, 15, 15, 5, 3><<<768, 256, 0, stream>>>(
      pose1, a1, dw1_w, dw1_bu, dw1_ba, pose2, a2);
  cc_em_kernel<8><<<1800, 256, 0, stream>>>(pose2, a2, cc1_w, cc1_bu, cc1_ba, pose3, a3);
  dw_caps_kernel<5, 16, 15, 15, 8, 8, 8, 1><<<512, 256, 0, stream>>>(
      pose3, a3, dw2_w, dw2_bu, dw2_ba, pose4, a4);
  cc_em_kernel<16><<<512, 256, 0, stream>>>(pose4, a4, cc2_w, cc2_bu, cc2_ba, pose5, a5);
  cls_m_kernel<<<320, 256, 0, stream>>>(pose5, a5, Xbuf, cls_w, cls_bu, cls_ba,
                                        mu_g, inv2_g, base_g, out, 1, 0);
  cls_e_kernel<<<64, 512, 0, stream>>>(pose5, a5, cls_w, mu_g, inv2_g, base_g, Xbuf);
  cls_m_kernel<<<320, 256, 0, stream>>>(pose5, a5, Xbuf, cls_w, cls_bu, cls_ba,
                                        mu_g, inv2_g, base_g, out, 0, 0);
  cls_e_kernel<<<64, 512, 0, stream>>>(pose5, a5, cls_w, mu_g, inv2_g, base_g, Xbuf);
  cls_m_kernel<<<320, 256, 0, stream>>>(pose5, a5, Xbuf, cls_w, cls_bu, cls_ba,
                                        mu_g, inv2_g, base_g, out, 0, 1);
}